// Round 3
// baseline (35.311 us; speedup 1.0000x reference)
//
#include <hip/hip_runtime.h>

// Shapes (fixed by setup_inputs):
//   zs   (128,256,1024) f32     rzs (128,256,1024) f32
//   pts  (128,256,118,2) f32    best (128,118,2) f32
//   qy   (128,256,64) f32       gts (128,128,118,2) f32
//   best_gt (128,118,2) f32     mapping (128,128) i32
//   vector_dims scalar = 64

namespace {
constexpr int NBLOCKS = 2048;
constexpr int NTHREADS = 256;
constexpr int STRIDE = NBLOCKS * NTHREADS;      // 524288 — compile-time!
constexpr int NA4 = 128 * 256 * 64 / 4;         // 524288 = 1 * STRIDE exactly
constexpr int NB4 = 128 * 128 * 1024 / 4;       // 4194304 = 8 * STRIDE exactly
constexpr int NC4 = 128 * 128 * 59;             // 966656 float4 (59 per point-row)
constexpr int ND4 = 128 * 59;                   // 7552
}

__global__ __launch_bounds__(256) void fused_loss(
    const float* __restrict__ zs, const float* __restrict__ rzs,
    const float* __restrict__ pts, const float* __restrict__ best,
    const float* __restrict__ qy, const float* __restrict__ gts,
    const float* __restrict__ best_gt, const int* __restrict__ mapping,
    double* __restrict__ partials)
{
    const int tid = blockIdx.x * NTHREADS + threadIdx.x;
    const float logV = 4.1588830833596715f;  // log(64)

    double accA = 0.0, accB = 0.0, accC = 0.0, accCm = 0.0, accD = 0.0, accDm = 0.0;

    // ---- Segment A: KLD — exactly one float4 per thread ----
    {
        const float4* qy4 = reinterpret_cast<const float4*>(qy);
        float4 q = qy4[tid];
        float s = q.x * (logf(q.x + 1e-20f) + logV)
                + q.y * (logf(q.y + 1e-20f) + logV)
                + q.z * (logf(q.z + 1e-20f) + logV)
                + q.w * (logf(q.w + 1e-20f) + logV);
        accA = (double)s;
    }

    // ---- Segment B: ae = mse(rzs[b,map[b,i],:], zs[b,i,:]) — 8 iters, unrolled ----
    {
        const float4* rzs4 = reinterpret_cast<const float4*>(rzs);
        const float4* zs4  = reinterpret_cast<const float4*>(zs);
#pragma unroll
        for (int k = 0; k < 8; ++k) {
            int idx = tid + k * STRIDE;     // < NB4 always (exact multiple)
            int off = idx & 255;            // float4 offset within D=1024 row
            int row = idx >> 8;             // b*128 + i
            int b   = row >> 7;
            int m   = mapping[row];
            float4 r = rzs4[(((b << 8) + m) << 8) + off];
            float4 z = zs4[((size_t)(row + (b << 7)) << 8) + off]; // zs[b,i]: b*256+i = row + b*128
            float dx = r.x - z.x, dy = r.y - z.y, dz = r.z - z.z, dw = r.w - z.w;
            accB += (double)(dx * dx + dy * dy + dz * dz + dw * dw);
        }
    }

    // ---- Segment C: bias = mse(pts[b,map[b,i]], gts[b,i]) + marked — 2 iters ----
    {
        const float4* pts4 = reinterpret_cast<const float4*>(pts);
        const float4* gts4 = reinterpret_cast<const float4*>(gts);
#pragma unroll
        for (int k = 0; k < 2; ++k) {
            int idx = tid + k * STRIDE;
            if (idx < NC4) {
                unsigned row = (unsigned)idx / 59u;   // b*128 + i
                int j = idx - (int)row * 59;          // float4 index: points 2j, 2j+1
                int b = (int)(row >> 7);
                int m = mapping[row];
                float4 pt = pts4[((b << 8) + m) * 59 + j];
                float4 g  = gts4[(int)row * 59 + j];
                float dx = pt.x - g.x, dy = pt.y - g.y;
                float dz = pt.z - g.z, dw = pt.w - g.w;
                float sq_lo = dx * dx + dy * dy;      // point 2j
                float sq_hi = dz * dz + dw * dw;      // point 2j+1
                accC += (double)(sq_lo + sq_hi);
                if (j == 0 || j == 44) accCm += (double)sq_lo;   // points 0, 88
                if (j == 14 || j == 58) accCm += (double)sq_hi;  // points 29, 117
            }
        }
    }

    // ---- Segment D: best mse + marked — one float4 for tid < 7552 ----
    if (tid < ND4) {
        const float4* best4 = reinterpret_cast<const float4*>(best);
        const float4* bgt4  = reinterpret_cast<const float4*>(best_gt);
        unsigned bi = (unsigned)tid / 59u;
        int j = tid - (int)bi * 59;
        float4 pb = best4[tid];
        float4 g  = bgt4[tid];
        float dx = pb.x - g.x, dy = pb.y - g.y;
        float dz = pb.z - g.z, dw = pb.w - g.w;
        float sq_lo = dx * dx + dy * dy;
        float sq_hi = dz * dz + dw * dw;
        accD = (double)(sq_lo + sq_hi);
        if (j == 0 || j == 44) accDm += (double)sq_lo;
        if (j == 14 || j == 58) accDm += (double)sq_hi;
    }

    // weights: kld 1/(B*S), ae 1/(B*Sg*D), bias 1/(B*Sg*P*2) + 10/(B*Sg*8),
    //          best 1/(B*P*2) + 10/(B*8)
    double total = accA  * (1.0 / 32768.0)
                 + accB  * (1.0 / 16777216.0)
                 + accC  * (1.0 / 3866624.0)
                 + accCm * (10.0 / 131072.0)
                 + accD  * (1.0 / 30208.0)
                 + accDm * (10.0 / 1024.0);

    // ---- block reduce (wave shfl + LDS), one store per block ----
    for (int off = 32; off > 0; off >>= 1)
        total += __shfl_down(total, off, 64);
    __shared__ double wsum[4];
    int lane = threadIdx.x & 63;
    int wid  = threadIdx.x >> 6;
    if (lane == 0) wsum[wid] = total;
    __syncthreads();
    if (threadIdx.x == 0)
        partials[blockIdx.x] = wsum[0] + wsum[1] + wsum[2] + wsum[3];
}

__global__ __launch_bounds__(256) void finalize(
    const double* __restrict__ partials, float* __restrict__ out)
{
    double t = 0.0;
    for (int i = threadIdx.x; i < NBLOCKS; i += 256)
        t += partials[i];
    for (int off = 32; off > 0; off >>= 1)
        t += __shfl_down(t, off, 64);
    __shared__ double wsum[4];
    int lane = threadIdx.x & 63;
    int wid  = threadIdx.x >> 6;
    if (lane == 0) wsum[wid] = t;
    __syncthreads();
    if (threadIdx.x == 0)
        out[0] = (float)(wsum[0] + wsum[1] + wsum[2] + wsum[3]);
}

extern "C" void kernel_launch(void* const* d_in, const int* in_sizes, int n_in,
                              void* d_out, int out_size, void* d_ws, size_t ws_size,
                              hipStream_t stream) {
    const float* zs      = (const float*)d_in[0];
    const float* rzs     = (const float*)d_in[1];
    const float* pts     = (const float*)d_in[2];
    const float* best    = (const float*)d_in[3];
    const float* qy      = (const float*)d_in[4];
    const float* gts     = (const float*)d_in[5];
    const float* best_gt = (const float*)d_in[6];
    const int*   mapping = (const int*)d_in[7];

    double* partials = (double*)d_ws;  // 2048 doubles, written unconditionally

    fused_loss<<<NBLOCKS, NTHREADS, 0, stream>>>(zs, rzs, pts, best, qy, gts,
                                                 best_gt, mapping, partials);
    finalize<<<1, 256, 0, stream>>>(partials, (float*)d_out);
}

// Round 4
// 33.698 us; speedup vs baseline: 1.0479x; 1.0479x over previous
//
#include <hip/hip_runtime.h>

// Shapes (fixed by setup_inputs):
//   zs   (128,256,1024) f32     rzs (128,256,1024) f32
//   pts  (128,256,118,2) f32    best (128,118,2) f32
//   qy   (128,256,64) f32       gts (128,128,118,2) f32
//   best_gt (128,118,2) f32     mapping (128,128) i32
//   vector_dims scalar = 64

namespace {
constexpr int NBLOCKS = 1024;
constexpr int NTHREADS = 512;
constexpr int STRIDE = NBLOCKS * NTHREADS;      // 524288 — compile-time
constexpr int NA4 = 128 * 256 * 64 / 4;         // 524288 = 1 * STRIDE exactly
constexpr int NB4 = 128 * 128 * 1024 / 4;       // 4194304 = 8 * STRIDE exactly
constexpr int NC4 = 128 * 128 * 59;             // 966656 float4 rows of 59
constexpr int ND4 = 128 * 59;                   // 7552
}

__global__ __launch_bounds__(512) void fused_loss(
    const float* __restrict__ zs, const float* __restrict__ rzs,
    const float* __restrict__ pts, const float* __restrict__ best,
    const float* __restrict__ qy, const float* __restrict__ gts,
    const float* __restrict__ best_gt, const int* __restrict__ mapping,
    double* __restrict__ partials)
{
    const int tid = blockIdx.x * NTHREADS + threadIdx.x;
    const float logV = 4.1588830833596715f;  // log(64)

    double accA = 0.0, accB0 = 0.0, accB1 = 0.0;
    double accC = 0.0, accCm = 0.0, accD = 0.0, accDm = 0.0;

    // ---- Segment A: KLD — exactly one float4 per thread ----
    {
        const float4* qy4 = reinterpret_cast<const float4*>(qy);
        float4 q = qy4[tid];
        float s = q.x * (logf(q.x + 1e-20f) + logV)
                + q.y * (logf(q.y + 1e-20f) + logV)
                + q.z * (logf(q.z + 1e-20f) + logV)
                + q.w * (logf(q.w + 1e-20f) + logV);
        accA = (double)s;
    }

    // ---- Segment B: ae = mse(rzs[b,map[b,i],:], zs[b,i,:]) — 8 iters, unrolled,
    //      two independent f64 accumulators to break the add chain ----
    {
        const float4* rzs4 = reinterpret_cast<const float4*>(rzs);
        const float4* zs4  = reinterpret_cast<const float4*>(zs);
#pragma unroll
        for (int k = 0; k < 8; ++k) {
            int idx = tid + k * STRIDE;     // < NB4 always (exact multiple)
            int off = idx & 255;            // float4 offset within D=1024 row
            int row = idx >> 8;             // b*128 + i  (wave-uniform)
            int b   = row >> 7;
            int m   = mapping[row];
            float4 r = rzs4[(((b << 8) + m) << 8) + off];
            float4 z = zs4[((size_t)(row + (b << 7)) << 8) + off]; // b*256+i = row+b*128
            float dx = r.x - z.x, dy = r.y - z.y, dz = r.z - z.z, dw = r.w - z.w;
            double s = (double)(dx * dx + dy * dy + dz * dz + dw * dw);
            if (k & 1) accB1 += s; else accB0 += s;
        }
    }

    // ---- Segment C: bias = mse(pts[b,map[b,i]], gts[b,i]) + marked — 2 iters ----
    {
        const float4* pts4 = reinterpret_cast<const float4*>(pts);
        const float4* gts4 = reinterpret_cast<const float4*>(gts);
#pragma unroll
        for (int k = 0; k < 2; ++k) {
            int idx = tid + k * STRIDE;
            if (idx < NC4) {
                unsigned row = (unsigned)idx / 59u;   // b*128 + i
                int j = idx - (int)row * 59;          // float4 idx: points 2j, 2j+1
                int b = (int)(row >> 7);
                int m = mapping[row];
                float4 pt = pts4[((b << 8) + m) * 59 + j];
                float4 g  = gts4[(int)row * 59 + j];
                float dx = pt.x - g.x, dy = pt.y - g.y;
                float dz = pt.z - g.z, dw = pt.w - g.w;
                float sq_lo = dx * dx + dy * dy;      // point 2j
                float sq_hi = dz * dz + dw * dw;      // point 2j+1
                accC += (double)(sq_lo + sq_hi);
                if (j == 0 || j == 44) accCm += (double)sq_lo;   // points 0, 88
                if (j == 14 || j == 58) accCm += (double)sq_hi;  // points 29, 117
            }
        }
    }

    // ---- Segment D: best mse + marked — one float4 for tid < 7552 ----
    if (tid < ND4) {
        const float4* best4 = reinterpret_cast<const float4*>(best);
        const float4* bgt4  = reinterpret_cast<const float4*>(best_gt);
        unsigned bi = (unsigned)tid / 59u;
        int j = tid - (int)bi * 59;
        float4 pb = best4[tid];
        float4 g  = bgt4[tid];
        float dx = pb.x - g.x, dy = pb.y - g.y;
        float dz = pb.z - g.z, dw = pb.w - g.w;
        float sq_lo = dx * dx + dy * dy;
        float sq_hi = dz * dz + dw * dw;
        accD = (double)(sq_lo + sq_hi);
        if (j == 0 || j == 44) accDm += (double)sq_lo;
        if (j == 14 || j == 58) accDm += (double)sq_hi;
    }

    // weights: kld 1/(B*S), ae 1/(B*Sg*D), bias 1/(B*Sg*P*2) + 10/(B*Sg*8),
    //          best 1/(B*P*2) + 10/(B*8)
    double total = accA  * (1.0 / 32768.0)
                 + (accB0 + accB1) * (1.0 / 16777216.0)
                 + accC  * (1.0 / 3866624.0)
                 + accCm * (10.0 / 131072.0)
                 + accD  * (1.0 / 30208.0)
                 + accDm * (10.0 / 1024.0);

    // ---- block reduce (wave shfl + LDS), one store per block ----
    for (int off = 32; off > 0; off >>= 1)
        total += __shfl_down(total, off, 64);
    __shared__ double wsum[8];
    int lane = threadIdx.x & 63;
    int wid  = threadIdx.x >> 6;
    if (lane == 0) wsum[wid] = total;
    __syncthreads();
    if (threadIdx.x == 0) {
        double t = wsum[0] + wsum[1] + wsum[2] + wsum[3]
                 + wsum[4] + wsum[5] + wsum[6] + wsum[7];
        partials[blockIdx.x] = t;
    }
}

__global__ __launch_bounds__(256) void finalize(
    const double* __restrict__ partials, float* __restrict__ out)
{
    // 256 threads × 4 slots each
    double t = 0.0;
#pragma unroll
    for (int k = 0; k < 4; ++k)
        t += partials[threadIdx.x + k * 256];
    for (int off = 32; off > 0; off >>= 1)
        t += __shfl_down(t, off, 64);
    __shared__ double wsum[4];
    int lane = threadIdx.x & 63;
    int wid  = threadIdx.x >> 6;
    if (lane == 0) wsum[wid] = t;
    __syncthreads();
    if (threadIdx.x == 0)
        out[0] = (float)(wsum[0] + wsum[1] + wsum[2] + wsum[3]);
}

extern "C" void kernel_launch(void* const* d_in, const int* in_sizes, int n_in,
                              void* d_out, int out_size, void* d_ws, size_t ws_size,
                              hipStream_t stream) {
    const float* zs      = (const float*)d_in[0];
    const float* rzs     = (const float*)d_in[1];
    const float* pts     = (const float*)d_in[2];
    const float* best    = (const float*)d_in[3];
    const float* qy      = (const float*)d_in[4];
    const float* gts     = (const float*)d_in[5];
    const float* best_gt = (const float*)d_in[6];
    const int*   mapping = (const int*)d_in[7];

    double* partials = (double*)d_ws;  // 1024 doubles, written unconditionally

    fused_loss<<<NBLOCKS, NTHREADS, 0, stream>>>(zs, rzs, pts, best, qy, gts,
                                                 best_gt, mapping, partials);
    finalize<<<1, 256, 0, stream>>>(partials, (float*)d_out);
}

// Round 5
// 33.640 us; speedup vs baseline: 1.0497x; 1.0017x over previous
//
#include <hip/hip_runtime.h>

// Shapes (fixed by setup_inputs):
//   zs   (128,256,1024) f32     rzs (128,256,1024) f32
//   pts  (128,256,118,2) f32    best (128,118,2) f32
//   qy   (128,256,64) f32       gts (128,128,118,2) f32
//   best_gt (128,118,2) f32     mapping (128,128) i32
//   vector_dims scalar = 64

typedef float f32x4 __attribute__((ext_vector_type(4)));

namespace {
constexpr int NBLOCKS = 1024;
constexpr int NTHREADS = 512;
constexpr int STRIDE = NBLOCKS * NTHREADS;      // 524288 — compile-time
constexpr int NA4 = 128 * 256 * 64 / 4;         // 524288 = 1 * STRIDE exactly
constexpr int NB4 = 128 * 128 * 1024 / 4;       // 4194304 = 8 * STRIDE exactly
constexpr int NC4 = 128 * 128 * 59;             // 966656 float4 rows of 59
constexpr int ND4 = 128 * 59;                   // 7552
}

__global__ __launch_bounds__(512) void fused_loss(
    const float* __restrict__ zs, const float* __restrict__ rzs,
    const float* __restrict__ pts, const float* __restrict__ best,
    const float* __restrict__ qy, const float* __restrict__ gts,
    const float* __restrict__ best_gt, const int* __restrict__ mapping,
    double* __restrict__ partials)
{
    const int tid = blockIdx.x * NTHREADS + threadIdx.x;
    const float logV = 4.1588830833596715f;  // log(64)

    double accA = 0.0, accB0 = 0.0, accB1 = 0.0;
    double accC = 0.0, accCm = 0.0, accD = 0.0, accDm = 0.0;

    // ---- Segment A: KLD — one nt float4 per thread (qy is single-use) ----
    {
        const f32x4* qy4 = reinterpret_cast<const f32x4*>(qy);
        f32x4 q = __builtin_nontemporal_load(qy4 + tid);
        float s = q.x * (logf(q.x + 1e-20f) + logV)
                + q.y * (logf(q.y + 1e-20f) + logV)
                + q.z * (logf(q.z + 1e-20f) + logV)
                + q.w * (logf(q.w + 1e-20f) + logV);
        accA = (double)s;
    }

    // ---- Segment B: ae = mse(rzs[b,map[b,i],:], zs[b,i,:]) — 8 iters, unrolled.
    //      zs is single-use -> nt load; rzs gather has ~21% duplicates -> cached.
    {
        const f32x4* rzs4 = reinterpret_cast<const f32x4*>(rzs);
        const f32x4* zs4  = reinterpret_cast<const f32x4*>(zs);
#pragma unroll
        for (int k = 0; k < 8; ++k) {
            int idx = tid + k * STRIDE;     // < NB4 always (exact multiple)
            int off = idx & 255;            // float4 offset within D=1024 row
            int row = idx >> 8;             // b*128 + i  (wave-uniform)
            int b   = row >> 7;
            int m   = mapping[row];
            f32x4 r = rzs4[(((b << 8) + m) << 8) + off];
            f32x4 z = __builtin_nontemporal_load(
                          zs4 + (((size_t)(row + (b << 7))) << 8) + off);
            float dx = r.x - z.x, dy = r.y - z.y, dz = r.z - z.z, dw = r.w - z.w;
            double s = (double)(dx * dx + dy * dy + dz * dz + dw * dw);
            if (k & 1) accB1 += s; else accB0 += s;
        }
    }

    // ---- Segment C: bias = mse(pts[b,map[b,i]], gts[b,i]) + marked — 2 iters.
    //      gts single-use -> nt; pts gather -> cached.
    {
        const f32x4* pts4 = reinterpret_cast<const f32x4*>(pts);
        const f32x4* gts4 = reinterpret_cast<const f32x4*>(gts);
#pragma unroll
        for (int k = 0; k < 2; ++k) {
            int idx = tid + k * STRIDE;
            if (idx < NC4) {
                unsigned row = (unsigned)idx / 59u;   // b*128 + i
                int j = idx - (int)row * 59;          // float4 idx: points 2j, 2j+1
                int b = (int)(row >> 7);
                int m = mapping[row];
                f32x4 pt = pts4[((b << 8) + m) * 59 + j];
                f32x4 g  = __builtin_nontemporal_load(gts4 + (int)row * 59 + j);
                float dx = pt.x - g.x, dy = pt.y - g.y;
                float dz = pt.z - g.z, dw = pt.w - g.w;
                float sq_lo = dx * dx + dy * dy;      // point 2j
                float sq_hi = dz * dz + dw * dw;      // point 2j+1
                accC += (double)(sq_lo + sq_hi);
                if (j == 0 || j == 44) accCm += (double)sq_lo;   // points 0, 88
                if (j == 14 || j == 58) accCm += (double)sq_hi;  // points 29, 117
            }
        }
    }

    // ---- Segment D: best mse + marked — one float4 for tid < 7552 ----
    if (tid < ND4) {
        const f32x4* best4 = reinterpret_cast<const f32x4*>(best);
        const f32x4* bgt4  = reinterpret_cast<const f32x4*>(best_gt);
        unsigned bi = (unsigned)tid / 59u;
        int j = tid - (int)bi * 59;
        f32x4 pb = best4[tid];
        f32x4 g  = bgt4[tid];
        float dx = pb.x - g.x, dy = pb.y - g.y;
        float dz = pb.z - g.z, dw = pb.w - g.w;
        float sq_lo = dx * dx + dy * dy;
        float sq_hi = dz * dz + dw * dw;
        accD = (double)(sq_lo + sq_hi);
        if (j == 0 || j == 44) accDm += (double)sq_lo;
        if (j == 14 || j == 58) accDm += (double)sq_hi;
    }

    // weights: kld 1/(B*S), ae 1/(B*Sg*D), bias 1/(B*Sg*P*2) + 10/(B*Sg*8),
    //          best 1/(B*P*2) + 10/(B*8)
    double total = accA  * (1.0 / 32768.0)
                 + (accB0 + accB1) * (1.0 / 16777216.0)
                 + accC  * (1.0 / 3866624.0)
                 + accCm * (10.0 / 131072.0)
                 + accD  * (1.0 / 30208.0)
                 + accDm * (10.0 / 1024.0);

    // ---- block reduce (wave shfl + LDS), one store per block ----
    for (int off = 32; off > 0; off >>= 1)
        total += __shfl_down(total, off, 64);
    __shared__ double wsum[8];
    int lane = threadIdx.x & 63;
    int wid  = threadIdx.x >> 6;
    if (lane == 0) wsum[wid] = total;
    __syncthreads();
    if (threadIdx.x == 0) {
        double t = wsum[0] + wsum[1] + wsum[2] + wsum[3]
                 + wsum[4] + wsum[5] + wsum[6] + wsum[7];
        partials[blockIdx.x] = t;
    }
}

__global__ __launch_bounds__(256) void finalize(
    const double* __restrict__ partials, float* __restrict__ out)
{
    // 256 threads × 4 slots each
    double t = 0.0;
#pragma unroll
    for (int k = 0; k < 4; ++k)
        t += partials[threadIdx.x + k * 256];
    for (int off = 32; off > 0; off >>= 1)
        t += __shfl_down(t, off, 64);
    __shared__ double wsum[4];
    int lane = threadIdx.x & 63;
    int wid  = threadIdx.x >> 6;
    if (lane == 0) wsum[wid] = t;
    __syncthreads();
    if (threadIdx.x == 0)
        out[0] = (float)(wsum[0] + wsum[1] + wsum[2] + wsum[3]);
}

extern "C" void kernel_launch(void* const* d_in, const int* in_sizes, int n_in,
                              void* d_out, int out_size, void* d_ws, size_t ws_size,
                              hipStream_t stream) {
    const float* zs      = (const float*)d_in[0];
    const float* rzs     = (const float*)d_in[1];
    const float* pts     = (const float*)d_in[2];
    const float* best    = (const float*)d_in[3];
    const float* qy      = (const float*)d_in[4];
    const float* gts     = (const float*)d_in[5];
    const float* best_gt = (const float*)d_in[6];
    const int*   mapping = (const int*)d_in[7];

    double* partials = (double*)d_ws;  // 1024 doubles, written unconditionally

    fused_loss<<<NBLOCKS, NTHREADS, 0, stream>>>(zs, rzs, pts, best, qy, gts,
                                                 best_gt, mapping, partials);
    finalize<<<1, 256, 0, stream>>>(partials, (float*)d_out);
}

// Round 6
// 31.881 us; speedup vs baseline: 1.1076x; 1.0552x over previous
//
#include <hip/hip_runtime.h>

// Shapes (fixed by setup_inputs):
//   zs   (128,256,1024) f32     rzs (128,256,1024) f32
//   pts  (128,256,118,2) f32    best (128,118,2) f32
//   qy   (128,256,64) f32       gts (128,128,118,2) f32
//   best_gt (128,118,2) f32     mapping (128,128) i32
//   vector_dims scalar = 64

typedef float f32x4 __attribute__((ext_vector_type(4)));

namespace {
constexpr int NBLOCKS = 1024;
constexpr int NTHREADS = 512;
constexpr int STRIDE = NBLOCKS * NTHREADS;      // 524288 — compile-time
constexpr int NA4 = 128 * 256 * 64 / 4;         // 524288 = 1 * STRIDE exactly
constexpr int NB4 = 128 * 128 * 1024 / 4;       // 4194304 = 8 * STRIDE exactly
constexpr int NC4 = 128 * 128 * 59;             // 966656 float4 rows of 59
constexpr int ND4 = 128 * 59;                   // 7552
}

__global__ __launch_bounds__(512) void fused_loss(
    const float* __restrict__ zs, const float* __restrict__ rzs,
    const float* __restrict__ pts, const float* __restrict__ best,
    const float* __restrict__ qy, const float* __restrict__ gts,
    const float* __restrict__ best_gt, const int* __restrict__ mapping,
    double* __restrict__ partials)
{
    // XCD-chunked swizzle: dispatch d -> work id w so that each XCD's 128
    // blocks (d % 8 == const) cover 2 complete batches -> gather duplicates
    // become L2-local instead of cross-XCD HBM re-fetches.
    const int d = blockIdx.x;
    const int w = ((d & 7) << 7) + (d >> 3);    // bijective on [0,1024)
    const int tid = w * NTHREADS + threadIdx.x;
    const float logV = 4.1588830833596715f;  // log(64)

    double accA = 0.0, accB0 = 0.0, accB1 = 0.0;
    double accC = 0.0, accCm = 0.0, accD = 0.0, accDm = 0.0;

    // ---- Segment A: KLD — one nt float4 per thread ----
    {
        const f32x4* qy4 = reinterpret_cast<const f32x4*>(qy);
        f32x4 q = __builtin_nontemporal_load(qy4 + tid);
        float s = q.x * (logf(q.x + 1e-20f) + logV)
                + q.y * (logf(q.y + 1e-20f) + logV)
                + q.z * (logf(q.z + 1e-20f) + logV)
                + q.w * (logf(q.w + 1e-20f) + logV);
        accA = (double)s;
    }

    // ---- Segment C first (short, latency-bound): its loads overlap B's
    //      bandwidth phase instead of being exposed at the kernel tail ----
    {
        const f32x4* pts4 = reinterpret_cast<const f32x4*>(pts);
        const f32x4* gts4 = reinterpret_cast<const f32x4*>(gts);
#pragma unroll
        for (int k = 0; k < 2; ++k) {
            int idx = tid + k * STRIDE;
            if (idx < NC4) {
                unsigned row = (unsigned)idx / 59u;   // b*128 + i
                int j = idx - (int)row * 59;          // float4 idx: points 2j, 2j+1
                int b = (int)(row >> 7);
                int m = mapping[row];
                f32x4 pt = pts4[((b << 8) + m) * 59 + j];
                f32x4 g  = __builtin_nontemporal_load(gts4 + (int)row * 59 + j);
                float dx = pt.x - g.x, dy = pt.y - g.y;
                float dz = pt.z - g.z, dw = pt.w - g.w;
                float sq_lo = dx * dx + dy * dy;      // point 2j
                float sq_hi = dz * dz + dw * dw;      // point 2j+1
                accC += (double)(sq_lo + sq_hi);
                if (j == 0 || j == 44) accCm += (double)sq_lo;   // points 0, 88
                if (j == 14 || j == 58) accCm += (double)sq_hi;  // points 29, 117
            }
        }
    }

    // ---- Segment D (tiny) ----
    if (tid < ND4) {
        const f32x4* best4 = reinterpret_cast<const f32x4*>(best);
        const f32x4* bgt4  = reinterpret_cast<const f32x4*>(best_gt);
        unsigned bi = (unsigned)tid / 59u;
        int j = tid - (int)bi * 59;
        f32x4 pb = best4[tid];
        f32x4 g  = bgt4[tid];
        float dx = pb.x - g.x, dy = pb.y - g.y;
        float dz = pb.z - g.z, dw = pb.w - g.w;
        float sq_lo = dx * dx + dy * dy;
        float sq_hi = dz * dz + dw * dw;
        accD = (double)(sq_lo + sq_hi);
        if (j == 0 || j == 44) accDm += (double)sq_lo;
        if (j == 14 || j == 58) accDm += (double)sq_hi;
    }

    // ---- Segment B: ae = mse(rzs[b,map[b,i],:], zs[b,i,:]) — 8 iters ----
    {
        const f32x4* rzs4 = reinterpret_cast<const f32x4*>(rzs);
        const f32x4* zs4  = reinterpret_cast<const f32x4*>(zs);
#pragma unroll
        for (int k = 0; k < 8; ++k) {
            int idx = tid + k * STRIDE;     // < NB4 always (exact multiple)
            int off = idx & 255;            // float4 offset within D=1024 row
            int row = idx >> 8;             // b*128 + i  (wave-uniform)
            int b   = row >> 7;
            int m   = mapping[row];
            f32x4 r = rzs4[(((b << 8) + m) << 8) + off];
            f32x4 z = __builtin_nontemporal_load(
                          zs4 + (((size_t)(row + (b << 7))) << 8) + off);
            float dx = r.x - z.x, dy = r.y - z.y, dz = r.z - z.z, dw = r.w - z.w;
            double s = (double)(dx * dx + dy * dy + dz * dz + dw * dw);
            if (k & 1) accB1 += s; else accB0 += s;
        }
    }

    // weights: kld 1/(B*S), ae 1/(B*Sg*D), bias 1/(B*Sg*P*2) + 10/(B*Sg*8),
    //          best 1/(B*P*2) + 10/(B*8)
    double total = accA  * (1.0 / 32768.0)
                 + (accB0 + accB1) * (1.0 / 16777216.0)
                 + accC  * (1.0 / 3866624.0)
                 + accCm * (10.0 / 131072.0)
                 + accD  * (1.0 / 30208.0)
                 + accDm * (10.0 / 1024.0);

    // ---- block reduce (wave shfl + LDS), one store per block ----
    for (int off = 32; off > 0; off >>= 1)
        total += __shfl_down(total, off, 64);
    __shared__ double wsum[8];
    int lane = threadIdx.x & 63;
    int wid  = threadIdx.x >> 6;
    if (lane == 0) wsum[wid] = total;
    __syncthreads();
    if (threadIdx.x == 0) {
        double t = wsum[0] + wsum[1] + wsum[2] + wsum[3]
                 + wsum[4] + wsum[5] + wsum[6] + wsum[7];
        partials[blockIdx.x] = t;   // order irrelevant to the sum
    }
}

__global__ __launch_bounds__(256) void finalize(
    const double* __restrict__ partials, float* __restrict__ out)
{
    double t = 0.0;
#pragma unroll
    for (int k = 0; k < 4; ++k)
        t += partials[threadIdx.x + k * 256];
    for (int off = 32; off > 0; off >>= 1)
        t += __shfl_down(t, off, 64);
    __shared__ double wsum[4];
    int lane = threadIdx.x & 63;
    int wid  = threadIdx.x >> 6;
    if (lane == 0) wsum[wid] = t;
    __syncthreads();
    if (threadIdx.x == 0)
        out[0] = (float)(wsum[0] + wsum[1] + wsum[2] + wsum[3]);
}

extern "C" void kernel_launch(void* const* d_in, const int* in_sizes, int n_in,
                              void* d_out, int out_size, void* d_ws, size_t ws_size,
                              hipStream_t stream) {
    const float* zs      = (const float*)d_in[0];
    const float* rzs     = (const float*)d_in[1];
    const float* pts     = (const float*)d_in[2];
    const float* best    = (const float*)d_in[3];
    const float* qy      = (const float*)d_in[4];
    const float* gts     = (const float*)d_in[5];
    const float* best_gt = (const float*)d_in[6];
    const int*   mapping = (const int*)d_in[7];

    double* partials = (double*)d_ws;  // 1024 doubles, written unconditionally

    fused_loss<<<NBLOCKS, NTHREADS, 0, stream>>>(zs, rzs, pts, best, qy, gts,
                                                 best_gt, mapping, partials);
    finalize<<<1, 256, 0, stream>>>(partials, (float*)d_out);
}